// Round 1
// baseline (14393.913 us; speedup 1.0000x reference)
//
#include <hip/hip_runtime.h>
#include <hip/hip_bf16.h>
#include <cmath>

// Problem constants (from reference setup_inputs)
#define NN 100000   // nodes
#define EE 600000   // edges
#define BB 512      // graphs
#define LL 10       // labels
// H = 128; dims: L1 256->512, L2 512->256, L3 256->128, L4 128->128, L5 128->10

__device__ __forceinline__ float elu_f(float x){ return x > 0.f ? x : expm1f(x); }

// Monotone float<->uint encoding for atomic max/min on floats
__device__ __forceinline__ unsigned enc_f(float f){
  unsigned u = __float_as_uint(f);
  return (u & 0x80000000u) ? ~u : (u | 0x80000000u);
}
__device__ __forceinline__ float dec_f(unsigned u){
  return (u & 0x80000000u) ? __uint_as_float(u ^ 0x80000000u) : __uint_as_float(~u);
}
#define ENC_NEG_INF 0x007FFFFFu  // enc(-inf)

__device__ __forceinline__ void fma8(float* acc, float a, float4 w0, float4 w1){
  acc[0] += a*w0.x; acc[1] += a*w0.y; acc[2] += a*w0.z; acc[3] += a*w0.w;
  acc[4] += a*w1.x; acc[5] += a*w1.y; acc[6] += a*w1.z; acc[7] += a*w1.w;
}

// ---------------------------------------------------------------------------
// kPQ: P = reps @ W1[0:128,:], Q = reps @ W1[128:256,:]   (reps = r0 - r1)
// Tile: 64 nodes x 128 cols, 256 threads; each thread 4 nodes x 8 cols x {P,Q}
// ---------------------------------------------------------------------------
__global__ __launch_bounds__(256) void kPQ(const float* __restrict__ r0,
                                           const float* __restrict__ r1,
                                           const float* __restrict__ W1,
                                           float* __restrict__ P,
                                           float* __restrict__ Q){
  __shared__ float sA[64*129];  // reps tile, stride 129 (2-way LDS aliasing = free)
  const int tid = threadIdx.x;
  const int tile_n = blockIdx.x * 64;
  const int ct = blockIdx.y * 128;

  #pragma unroll
  for (int u = 0; u < 8; ++u){
    int idx4 = tid * 8 + u;        // 2048 float4-groups of the 64x128 tile
    int row = idx4 >> 5;
    int k4 = (idx4 & 31) << 2;
    int gr = tile_n + row; if (gr > NN-1) gr = NN-1;  // clamp loads; stores guarded
    float4 a = *(const float4*)(r0 + (size_t)gr*128 + k4);
    float4 b = *(const float4*)(r1 + (size_t)gr*128 + k4);
    float* d = sA + row*129 + k4;
    d[0]=a.x-b.x; d[1]=a.y-b.y; d[2]=a.z-b.z; d[3]=a.w-b.w;
  }
  __syncthreads();

  const int c = tid & 15;   // 16 col groups x 8 cols
  const int g = tid >> 4;   // 16 node groups x 4 nodes
  const int n0 = ct + c*8;
  float accP[4][8], accQ[4][8];
  #pragma unroll
  for (int i=0;i<4;++i)
    #pragma unroll
    for (int n=0;n<8;++n){ accP[i][n]=0.f; accQ[i][n]=0.f; }

  #pragma unroll 2
  for (int k = 0; k < 128; ++k){
    float4 wp0 = *(const float4*)(W1 + (size_t)k*512 + n0);
    float4 wp1 = *(const float4*)(W1 + (size_t)k*512 + n0 + 4);
    float4 wq0 = *(const float4*)(W1 + (size_t)(k+128)*512 + n0);
    float4 wq1 = *(const float4*)(W1 + (size_t)(k+128)*512 + n0 + 4);
    #pragma unroll
    for (int i=0;i<4;++i){
      float a = sA[(g*4+i)*129 + k];
      fma8(accP[i], a, wp0, wp1);
      fma8(accQ[i], a, wq0, wq1);
    }
  }

  #pragma unroll
  for (int i=0;i<4;++i){
    int gr = tile_n + g*4 + i;
    if (gr < NN){
      float* p = P + (size_t)gr*512 + n0;
      float* q = Q + (size_t)gr*512 + n0;
      *(float4*)(p)   = make_float4(accP[i][0],accP[i][1],accP[i][2],accP[i][3]);
      *(float4*)(p+4) = make_float4(accP[i][4],accP[i][5],accP[i][6],accP[i][7]);
      *(float4*)(q)   = make_float4(accQ[i][0],accQ[i][1],accQ[i][2],accQ[i][3]);
      *(float4*)(q+4) = make_float4(accQ[i][4],accQ[i][5],accQ[i][6],accQ[i][7]);
    }
  }
}

// ---------------------------------------------------------------------------
// kEdgeMLP: fused layers 1..5 -> scores[E], ebatch[E].
// 32 edges per workgroup, 256 threads. LDS region union keeps static LDS < 64KB:
//   regA (8256 f): tier-C rs/rd (2x 32x129)  then  sh2 (32x257)
//   sh1  (2080 f): h1 64-col chunk
//   sh3  (4128 f): h3 tile
// ---------------------------------------------------------------------------
template<bool USE_PQ>
__global__ __launch_bounds__(256) void kEdgeMLP(
    const float* __restrict__ r0, const float* __restrict__ r1,
    const float* __restrict__ P,  const float* __restrict__ Q,
    const float* __restrict__ W1, const float* __restrict__ b1,
    const float* __restrict__ W2, const float* __restrict__ b2,
    const float* __restrict__ W3, const float* __restrict__ b3,
    const float* __restrict__ W4, const float* __restrict__ b4,
    const float* __restrict__ W5, const float* __restrict__ b5,
    const int* __restrict__ edge_index, const int* __restrict__ batch,
    const int* __restrict__ y,
    float* __restrict__ scores, int* __restrict__ ebatch)
{
  __shared__ float regA[8256];
  __shared__ float sh1[32*65];
  __shared__ float sh3[32*129];
  __shared__ int ssrc[32], sdst[32], sty[32], seb[32];
  float* rs  = regA;             // [32][129] (tier C only)
  float* rd  = regA + 32*129;
  float* sh2 = regA;             // [32][257] (after chunk loop)

  const int tid = threadIdx.x;
  const int e0 = blockIdx.x * 32;

  if (tid < 32){
    int s = edge_index[e0 + tid];
    int d = edge_index[EE + e0 + tid];
    ssrc[tid] = s; sdst[tid] = d;
    int eb = batch[s];
    seb[tid] = eb;
    sty[tid] = y[eb];
  }
  __syncthreads();

  if (!USE_PQ){
    // stage rs/rd = (r0 - r1) rows of src/dst: 8 threads x 16 floats per edge
    const int e = tid >> 3, part = tid & 7;
    const int s = ssrc[e], d = sdst[e];
    #pragma unroll
    for (int u = 0; u < 4; ++u){
      int k = part*16 + u*4;
      float4 a  = *(const float4*)(r0 + (size_t)s*128 + k);
      float4 b  = *(const float4*)(r1 + (size_t)s*128 + k);
      float* dp = rs + e*129 + k;
      dp[0]=a.x-b.x; dp[1]=a.y-b.y; dp[2]=a.z-b.z; dp[3]=a.w-b.w;
      float4 c0 = *(const float4*)(r0 + (size_t)d*128 + k);
      float4 c1 = *(const float4*)(r1 + (size_t)d*128 + k);
      float* dq = rd + e*129 + k;
      dq[0]=c0.x-c1.x; dq[1]=c0.y-c1.y; dq[2]=c0.z-c1.z; dq[3]=c0.w-c1.w;
    }
    __syncthreads();
  }

  // ---- layers 1+2: h2 = elu(elu(h1) @ W2 + b2), K=512 chunked by 64 ----
  const int c8 = tid & 31;   // 32 col groups x 8 cols of 256
  const int g8 = tid >> 5;   // 8 edge groups x 4 edges
  float acc2[4][8];
  #pragma unroll
  for (int i=0;i<4;++i)
    #pragma unroll
    for (int n=0;n<8;++n) acc2[i][n] = 0.f;

  const int eS = tid >> 3;        // sh1 build: 8 threads per edge
  const int m0 = (tid & 7) * 8;   // 8 cols of the 64-col chunk

  for (int kc = 0; kc < 512; kc += 64){
    float v[8];
    if (USE_PQ){
      const float* Pr = P + (size_t)ssrc[eS]*512 + kc + m0;
      const float* Qr = Q + (size_t)sdst[eS]*512 + kc + m0;
      float4 p0 = *(const float4*)Pr,     p1 = *(const float4*)(Pr+4);
      float4 q0 = *(const float4*)Qr,     q1 = *(const float4*)(Qr+4);
      v[0]=p0.x+q0.x; v[1]=p0.y+q0.y; v[2]=p0.z+q0.z; v[3]=p0.w+q0.w;
      v[4]=p1.x+q1.x; v[5]=p1.y+q1.y; v[6]=p1.z+q1.z; v[7]=p1.w+q1.w;
    } else {
      #pragma unroll
      for (int n=0;n<8;++n) v[n] = 0.f;
      #pragma unroll 2
      for (int k = 0; k < 128; ++k){
        float a = rs[eS*129 + k];
        float b = rd[eS*129 + k];
        float4 w0 = *(const float4*)(W1 + (size_t)k*512 + kc + m0);
        float4 w1 = *(const float4*)(W1 + (size_t)k*512 + kc + m0 + 4);
        float4 x0 = *(const float4*)(W1 + (size_t)(k+128)*512 + kc + m0);
        float4 x1 = *(const float4*)(W1 + (size_t)(k+128)*512 + kc + m0 + 4);
        v[0] += a*w0.x + b*x0.x; v[1] += a*w0.y + b*x0.y;
        v[2] += a*w0.z + b*x0.z; v[3] += a*w0.w + b*x0.w;
        v[4] += a*w1.x + b*x1.x; v[5] += a*w1.y + b*x1.y;
        v[6] += a*w1.z + b*x1.z; v[7] += a*w1.w + b*x1.w;
      }
    }
    {
      float* dp = sh1 + eS*65 + m0;
      #pragma unroll
      for (int n = 0; n < 8; ++n) dp[n] = elu_f(v[n] + b1[kc + m0 + n]);
    }
    __syncthreads();
    #pragma unroll 4
    for (int k = 0; k < 64; ++k){
      float4 w0 = *(const float4*)(W2 + (size_t)(kc+k)*256 + c8*8);
      float4 w1 = *(const float4*)(W2 + (size_t)(kc+k)*256 + c8*8 + 4);
      #pragma unroll
      for (int i = 0; i < 4; ++i){
        float a = sh1[(g8*4+i)*65 + k];
        fma8(acc2[i], a, w0, w1);
      }
    }
    __syncthreads();  // before sh1 overwrite next chunk (also fences rs/rd reads)
  }

  // layer2 epilogue -> sh2 (overwrites regA; rs/rd dead)
  #pragma unroll
  for (int i = 0; i < 4; ++i){
    int e = g8*4 + i;
    #pragma unroll
    for (int n = 0; n < 8; ++n)
      sh2[e*257 + c8*8 + n] = elu_f(acc2[i][n] + b2[c8*8 + n]);
  }
  __syncthreads();

  // ---- layer 3: h3 = h2 @ W3 + b3 (no activation) ----
  const int c16 = tid & 15, g16 = tid >> 4;
  float acc3[2][8];
  #pragma unroll
  for (int i=0;i<2;++i)
    #pragma unroll
    for (int n=0;n<8;++n) acc3[i][n] = 0.f;
  #pragma unroll 2
  for (int k = 0; k < 256; ++k){
    float4 w0 = *(const float4*)(W3 + (size_t)k*128 + c16*8);
    float4 w1 = *(const float4*)(W3 + (size_t)k*128 + c16*8 + 4);
    #pragma unroll
    for (int i = 0; i < 2; ++i){
      float a = sh2[(g16*2+i)*257 + k];
      fma8(acc3[i], a, w0, w1);
    }
  }
  #pragma unroll
  for (int i = 0; i < 2; ++i){
    int e = g16*2 + i;
    #pragma unroll
    for (int n = 0; n < 8; ++n)
      sh3[e*129 + c16*8 + n] = acc3[i][n] + b3[c16*8 + n];
  }
  __syncthreads();

  // ---- layers 4+5: score = elu(h3 @ W4 + b4) . W5[:,t] + b5[t] ----
  const int eL = tid >> 3, jg = tid & 7;  // 8 threads/edge, 16 j's each
  float acc5[16];
  #pragma unroll
  for (int j=0;j<16;++j) acc5[j] = 0.f;
  #pragma unroll 2
  for (int k = 0; k < 128; ++k){
    float a = sh3[eL*129 + k];
    const float4* w = (const float4*)(W4 + (size_t)k*128 + jg*16);
    float4 w0 = w[0], w1 = w[1], w2v = w[2], w3v = w[3];
    acc5[0] += a*w0.x;  acc5[1] += a*w0.y;  acc5[2] += a*w0.z;  acc5[3] += a*w0.w;
    acc5[4] += a*w1.x;  acc5[5] += a*w1.y;  acc5[6] += a*w1.z;  acc5[7] += a*w1.w;
    acc5[8] += a*w2v.x; acc5[9] += a*w2v.y; acc5[10]+= a*w2v.z; acc5[11]+= a*w2v.w;
    acc5[12]+= a*w3v.x; acc5[13]+= a*w3v.y; acc5[14]+= a*w3v.z; acc5[15]+= a*w3v.w;
  }
  const int t = sty[eL];
  float s = 0.f;
  #pragma unroll
  for (int jj = 0; jj < 16; ++jj){
    int j = jg*16 + jj;
    float h = elu_f(acc5[jj] + b4[j]);
    s += h * W5[j*LL + t];
  }
  s += __shfl_down(s, 4, 8);
  s += __shfl_down(s, 2, 8);
  s += __shfl_down(s, 1, 8);
  if (jg == 0){
    scores[e0 + eL] = s + b5[t];
    ebatch[e0 + eL] = seb[eL];
  }
}

// ---------------------------------------------------------------------------
// Segment softmax / argmax passes (B=512 segments, LDS pre-reduction)
// ---------------------------------------------------------------------------
__global__ void kInitSeg(unsigned* segmax, float* segsum, unsigned* gmax, int* gact){
  int b = blockIdx.x*blockDim.x + threadIdx.x;
  if (b < BB){ segmax[b] = ENC_NEG_INF; segsum[b] = 0.f; gmax[b] = ENC_NEG_INF; gact[b] = 0x7FFFFFFF; }
}

__global__ __launch_bounds__(256) void kSegMax(const float* __restrict__ scores,
                                               const int* __restrict__ eb,
                                               unsigned* __restrict__ segmax){
  __shared__ unsigned l[BB];
  for (int b = threadIdx.x; b < BB; b += 256) l[b] = 0u;
  __syncthreads();
  for (int e = blockIdx.x*256 + threadIdx.x; e < EE; e += gridDim.x*256)
    atomicMax(&l[eb[e]], enc_f(scores[e]));
  __syncthreads();
  for (int b = threadIdx.x; b < BB; b += 256)
    if (l[b]) atomicMax(&segmax[b], l[b]);
}

__global__ __launch_bounds__(256) void kExpSum(const float* __restrict__ scores,
                                               const int* __restrict__ eb,
                                               const unsigned* __restrict__ segmax,
                                               float* __restrict__ segsum,
                                               float* __restrict__ outprobs){
  __shared__ float l[BB];
  for (int b = threadIdx.x; b < BB; b += 256) l[b] = 0.f;
  __syncthreads();
  for (int e = blockIdx.x*256 + threadIdx.x; e < EE; e += gridDim.x*256){
    int b = eb[e];
    float ex = expf(scores[e] - dec_f(segmax[b]));
    outprobs[e] = ex;                       // stash ex in d_out, rescaled next pass
    atomicAdd(&l[b], ex);
  }
  __syncthreads();
  for (int b = threadIdx.x; b < BB; b += 256)
    if (l[b] != 0.f) atomicAdd(&segsum[b], l[b]);
}

__global__ __launch_bounds__(256) void kProbMax(float* __restrict__ outprobs,
                                                const int* __restrict__ eb,
                                                const float* __restrict__ segsum,
                                                unsigned* __restrict__ gmax){
  __shared__ unsigned l[BB];
  for (int b = threadIdx.x; b < BB; b += 256) l[b] = 0u;
  __syncthreads();
  for (int e = blockIdx.x*256 + threadIdx.x; e < EE; e += gridDim.x*256){
    int b = eb[e];
    float p = outprobs[e] / segsum[b];
    outprobs[e] = p;
    atomicMax(&l[b], enc_f(p));
  }
  __syncthreads();
  for (int b = threadIdx.x; b < BB; b += 256)
    if (l[b]) atomicMax(&gmax[b], l[b]);
}

__global__ __launch_bounds__(256) void kArgMin(const float* __restrict__ outprobs,
                                               const int* __restrict__ eb,
                                               const unsigned* __restrict__ gmax,
                                               int* __restrict__ gact){
  __shared__ int l[BB];
  for (int b = threadIdx.x; b < BB; b += 256) l[b] = 0x7FFFFFFF;
  __syncthreads();
  for (int e = blockIdx.x*256 + threadIdx.x; e < EE; e += gridDim.x*256){
    int b = eb[e];
    if (enc_f(outprobs[e]) == gmax[b]) atomicMin(&l[b], e);
  }
  __syncthreads();
  for (int b = threadIdx.x; b < BB; b += 256)
    if (l[b] != 0x7FFFFFFF) atomicMin(&gact[b], l[b]);
}

__global__ void kFinal(const unsigned* __restrict__ gmax, const int* __restrict__ gact,
                       float* __restrict__ out){
  int b = threadIdx.x;
  if (b < BB){
    out[EE + b]      = dec_f(gmax[b]);
    out[EE + BB + b] = (float)gact[b];   // indices < 2^24, exact in fp32
  }
}

// ---------------------------------------------------------------------------
extern "C" void kernel_launch(void* const* d_in, const int* in_sizes, int n_in,
                              void* d_out, int out_size, void* d_ws, size_t ws_size,
                              hipStream_t stream){
  const float* r0 = (const float*)d_in[0];
  const float* r1 = (const float*)d_in[1];
  const float* W1 = (const float*)d_in[2];
  const float* b1 = (const float*)d_in[3];
  const float* W2 = (const float*)d_in[4];
  const float* b2 = (const float*)d_in[5];
  const float* W3 = (const float*)d_in[6];
  const float* b3 = (const float*)d_in[7];
  const float* W4 = (const float*)d_in[8];
  const float* b4 = (const float*)d_in[9];
  const float* W5 = (const float*)d_in[10];
  const float* b5 = (const float*)d_in[11];
  const int* edge_index = (const int*)d_in[12];
  const int* batch = (const int*)d_in[13];
  const int* y = (const int*)d_in[14];
  float* out = (float*)d_out;

  char* ws = (char*)d_ws;
  size_t off = 0;
  float*    scores = (float*)(ws + off);   off += (size_t)EE*4;
  int*      ebatch = (int*)(ws + off);     off += (size_t)EE*4;
  unsigned* segmax = (unsigned*)(ws + off); off += BB*4;
  float*    segsum = (float*)(ws + off);   off += BB*4;
  unsigned* gmax   = (unsigned*)(ws + off); off += BB*4;
  int*      gact   = (int*)(ws + off);     off += BB*4;
  off = (off + 511) & ~(size_t)511;
  float* P = (float*)(ws + off);
  float* Q = P + (size_t)NN*512;
  size_t needPQ = off + 2ull*NN*512*4;
  bool usePQ = (ws_size >= needPQ);  // host-side, deterministic -> capture-safe

  kInitSeg<<<2, 256, 0, stream>>>(segmax, segsum, gmax, gact);

  if (usePQ){
    kPQ<<<dim3((NN+63)/64, 4), 256, 0, stream>>>(r0, r1, W1, P, Q);
    kEdgeMLP<true><<<EE/32, 256, 0, stream>>>(r0, r1, P, Q, W1, b1, W2, b2, W3, b3,
                                              W4, b4, W5, b5, edge_index, batch, y,
                                              scores, ebatch);
  } else {
    kEdgeMLP<false><<<EE/32, 256, 0, stream>>>(r0, r1, P, Q, W1, b1, W2, b2, W3, b3,
                                               W4, b4, W5, b5, edge_index, batch, y,
                                               scores, ebatch);
  }

  kSegMax <<<256, 256, 0, stream>>>(scores, ebatch, segmax);
  kExpSum <<<256, 256, 0, stream>>>(scores, ebatch, segmax, segsum, out);
  kProbMax<<<256, 256, 0, stream>>>(out, ebatch, segsum, gmax);
  kArgMin <<<256, 256, 0, stream>>>(out, ebatch, gmax, gact);
  kFinal  <<<1, 512, 0, stream>>>(gmax, gact, out);
}

// Round 2
// 3484.578 us; speedup vs baseline: 4.1307x; 4.1307x over previous
//
#include <hip/hip_runtime.h>
#include <hip/hip_bf16.h>
#include <cmath>

#define NN 100000   // nodes
#define EE 600000   // edges
#define BB 512      // graphs
#define LL 10       // labels
// H=128; L1 256->512, L2 512->256, L3 256->128, L4 128->128, L5 128->10 (col-picked)

typedef __attribute__((ext_vector_type(8))) short  bf16x8;
typedef __attribute__((ext_vector_type(4))) float  f32x4;
typedef unsigned int uint;
typedef unsigned short ushort;

__device__ __forceinline__ float elu_f(float x){ return x > 0.f ? x : expm1f(x); }

__device__ __forceinline__ ushort bf16_rne(float f){
  uint u = __float_as_uint(f);
  return (ushort)((u + 0x7FFFu + ((u >> 16) & 1u)) >> 16);
}

__device__ __forceinline__ f32x4 MFMA(bf16x8 a, bf16x8 b, f32x4 c){
  return __builtin_amdgcn_mfma_f32_16x16x32_bf16(a, b, c, 0, 0, 0);
}

// Monotone float<->uint encoding for atomic max/min on floats
__device__ __forceinline__ unsigned enc_f(float f){
  unsigned u = __float_as_uint(f);
  return (u & 0x80000000u) ? ~u : (u | 0x80000000u);
}
__device__ __forceinline__ float dec_f(unsigned u){
  return (u & 0x80000000u) ? __uint_as_float(u ^ 0x80000000u) : __uint_as_float(~u);
}
#define ENC_NEG_INF 0x007FFFFFu

// ---------------------------------------------------------------------------
// kReps: repsF[n] = 512B row: [16 chunks hi(k=0..127)][16 chunks lo], bf16 bits.
// ---------------------------------------------------------------------------
__global__ __launch_bounds__(256) void kReps(const float* __restrict__ r0,
                                             const float* __restrict__ r1,
                                             ushort* __restrict__ repsF){
  int gid = blockIdx.x*256 + threadIdx.x;          // N*16 threads
  int n = gid >> 4, k8 = gid & 15;
  const float4* a = (const float4*)(r0 + (size_t)n*128 + k8*8);
  const float4* b = (const float4*)(r1 + (size_t)n*128 + k8*8);
  float4 x0 = a[0], x1 = a[1], y0 = b[0], y1 = b[1];
  float d[8] = {x0.x-y0.x, x0.y-y0.y, x0.z-y0.z, x0.w-y0.w,
                x1.x-y1.x, x1.y-y1.y, x1.z-y1.z, x1.w-y1.w};
  ushort hi[8], lo[8];
  #pragma unroll
  for (int j=0;j<8;++j){
    hi[j] = bf16_rne(d[j]);
    float fh = __uint_as_float(((uint)hi[j])<<16);
    lo[j] = bf16_rne(d[j] - fh);
  }
  ushort* dh = repsF + (size_t)n*256 + k8*8;
  ushort* dl = dh + 128;
  #pragma unroll
  for (int j=0;j<8;++j){ dh[j] = hi[j]; dl[j] = lo[j]; }
}

// ---------------------------------------------------------------------------
// kPrepW: weight [K][N] fp32 -> MFMA-fragment bf16 hi/lo:
//   dst[part][kt][nt][lane][j] with k = kt*32+(l>>4)*8+j, n = nt*16+(l&15).
// ---------------------------------------------------------------------------
__global__ __launch_bounds__(256) void kPrepW(const float* __restrict__ W, int N,
                                              int KT, int NT, ushort* __restrict__ dst){
  int gid = blockIdx.x*256 + threadIdx.x;
  int total = KT*NT*64;
  if (gid >= total) return;
  int l = gid & 63, tile = gid >> 6;
  int kt = tile / NT, nt = tile % NT;
  int kbase = kt*32 + (l>>4)*8;
  int n = nt*16 + (l&15);
  int partStride = KT*NT*512;
  int base = tile*512 + l*8;
  #pragma unroll
  for (int j=0;j<8;++j){
    float f = W[(size_t)(kbase+j)*N + n];
    ushort h = bf16_rne(f);
    float fh = __uint_as_float(((uint)h)<<16);
    dst[base + j] = h;
    dst[partStride + base + j] = bf16_rne(f - fh);
  }
}

// ---------------------------------------------------------------------------
// kMLP: fused MFMA layers 1..5 for a 64-edge tile. 256 threads = 4 waves.
// LDS fragment-chunk layout: chunk(part,kg,m) at 16B index (base + kg*65 + m)
// — stride 65 makes frag reads phase-conflict-free and epilogue pair-writes
// exactly 2-way (free).  Regions (chunks of 16B, sAF = 4160 chunks = 66.5KB):
//   A1 [0,2080)  A2 [2080,4160)  A3 = whole (part*2080)  A4 = [0,2080)
// Wave w: m-tiles mtw=(w&1)*2..+1, n-half nth=w>>1  (2mt x 8nt per layer).
// ---------------------------------------------------------------------------
__global__ __launch_bounds__(256, 2) void kMLP(
    const ushort* __restrict__ repsF,
    const ushort* __restrict__ W1F, const ushort* __restrict__ W2F,
    const ushort* __restrict__ W3F, const ushort* __restrict__ W4F,
    const float* __restrict__ b1, const float* __restrict__ b2,
    const float* __restrict__ b3, const float* __restrict__ b4,
    const float* __restrict__ W5, const float* __restrict__ b5,
    const int* __restrict__ edge_index, const int* __restrict__ batch,
    const int* __restrict__ y,
    float* __restrict__ scores, int* __restrict__ ebatch)
{
  __shared__ __align__(16) short sAF[33280];   // 66560 B
  __shared__ float sScore[64];
  __shared__ int sTy[64], sEb[64];

  const int tid = threadIdx.x;
  const int w = tid >> 6, l = tid & 63;
  const int quad = l >> 4, r16 = l & 15;
  const int mtw = (w & 1) * 2;       // wave's m-tiles: mtw, mtw+1
  const int nth = w >> 1;            // wave's n-half
  const int e0 = blockIdx.x * 64;

  const int mg = tid & 63;           // gather: edge slot owned by this thread
  const int cg = tid >> 6;           // gather: chunk group (8 chunks)
  const int mysrc = edge_index[e0 + mg];
  const int mydst = edge_index[EE + e0 + mg];
  if (tid < 64){
    int eb = batch[mysrc];
    sEb[tid] = eb; sTy[tid] = y[eb]; sScore[tid] = 0.f;
  }

  uint* ldsu = (uint*)sAF;

  // ---- layers 1+2 ----
  f32x4 C2[16];
  #pragma unroll
  for (int i=0;i<16;++i) C2[i] = (f32x4)0.f;

  for (int kc = 0; kc < 2; ++kc){            // 256-col chunk of h1
    f32x4 C1[16];
    #pragma unroll
    for (int i=0;i<16;++i) C1[i] = (f32x4)0.f;

    for (int half = 0; half < 2; ++half){    // K: src rows then dst rows
      __syncthreads();                       // prior readers of A1 done
      {
        int node = half ? mydst : mysrc;
        const bf16x8* g = (const bf16x8*)(repsF + (size_t)node*256);
        #pragma unroll
        for (int i=0;i<8;++i){
          int c = cg*8 + i;                  // 0..31: <16 hi, else lo
          int part = c >> 4, kg = c & 15;
          *(bf16x8*)(sAF + (part*1040 + kg*65 + mg)*8) = g[c];
        }
      }
      __syncthreads();

      for (int kt4 = 0; kt4 < 4; ++kt4){
        bf16x8 Ah[2], Al[2];
        #pragma unroll
        for (int mtl=0;mtl<2;++mtl){
          int m = (mtw+mtl)*16 + r16;
          Ah[mtl] = *(const bf16x8*)(sAF + ((kt4*4+quad)*65 + m)*8);
          Al[mtl] = *(const bf16x8*)(sAF + (1040 + (kt4*4+quad)*65 + m)*8);
        }
        int ktAbs = half*4 + kt4;            // W1 k-tile (KT=8)
        const bf16x8* Wf = (const bf16x8*)W1F;
        #pragma unroll
        for (int ntl = 0; ntl < 8; ++ntl){
          int nt = kc*16 + nth*8 + ntl;      // 0..31 (NT=32)
          bf16x8 Bh = Wf[(ktAbs*32 + nt)*64 + l];
          bf16x8 Bl = Wf[(8*32*64) + (ktAbs*32 + nt)*64 + l];
          f32x4 c0 = C1[ntl*2+0], c1 = C1[ntl*2+1];
          c0 = MFMA(Ah[0], Bh, c0); c1 = MFMA(Ah[1], Bh, c1);
          c0 = MFMA(Ah[0], Bl, c0); c1 = MFMA(Ah[1], Bl, c1);
          c0 = MFMA(Al[0], Bh, c0); c1 = MFMA(Al[1], Bh, c1);
          C1[ntl*2+0] = c0; C1[ntl*2+1] = c1;
        }
      }
    }

    // sub-chunk epilogue (128 cols) -> A2, then layer-2 partial
    for (int sc = 0; sc < 2; ++sc){
      __syncthreads();                       // prior A2 readers done
      if (nth == sc){                        // owner waves write their frags
        #pragma unroll
        for (int ntl = 0; ntl < 8; ++ntl){
          #pragma unroll
          for (int mtl = 0; mtl < 2; ++mtl){
            f32x4 v = C1[ntl*2+mtl];
            int n = (kc*16 + sc*8 + ntl)*16 + r16;   // abs col of h1
            float bv = b1[n];
            ushort hi[4], lo[4];
            #pragma unroll
            for (int r=0;r<4;++r){
              float f = elu_f(v[r] + bv);
              hi[r] = bf16_rne(f);
              float fh = __uint_as_float(((uint)hi[r])<<16);
              lo[r] = bf16_rne(f - fh);
            }
            int k2 = ntl*16 + r16;                    // col within sub-chunk
            int kg = k2 >> 3, j = k2 & 7;
            int m0 = (mtw+mtl)*16 + quad*4;
            // lane-pair packed b32 writes (partner = l^1 shares the dword)
            uint v01h = (uint)hi[0] | ((uint)hi[1]<<16);
            uint v23h = (uint)hi[2] | ((uint)hi[3]<<16);
            uint v01l = (uint)lo[0] | ((uint)lo[1]<<16);
            uint v23l = (uint)lo[2] | ((uint)lo[3]<<16);
            uint t01h = __shfl_xor(v01h, 1), t23h = __shfl_xor(v23h, 1);
            uint t01l = __shfl_xor(v01l, 1), t23l = __shfl_xor(v23l, 1);
            int jj = (j & ~1) >> 1;
            int cbH = 2080 + 0*1040 + kg*65;          // A2 hi
            int cbL = 2080 + 1*1040 + kg*65;          // A2 lo
            if (!(l & 1)){
              ldsu[(cbH + m0 + 0)*4 + jj] = (v01h & 0xFFFFu) | (t01h << 16);
              ldsu[(cbH + m0 + 1)*4 + jj] = (v01h >> 16) | (t01h & 0xFFFF0000u);
              ldsu[(cbL + m0 + 0)*4 + jj] = (v01l & 0xFFFFu) | (t01l << 16);
              ldsu[(cbL + m0 + 1)*4 + jj] = (v01l >> 16) | (t01l & 0xFFFF0000u);
            } else {
              ldsu[(cbH + m0 + 2)*4 + jj] = (t23h & 0xFFFFu) | (v23h << 16);
              ldsu[(cbH + m0 + 3)*4 + jj] = (t23h >> 16) | (v23h & 0xFFFF0000u);
              ldsu[(cbL + m0 + 2)*4 + jj] = (t23l & 0xFFFFu) | (v23l << 16);
              ldsu[(cbL + m0 + 3)*4 + jj] = (t23l >> 16) | (v23l & 0xFFFF0000u);
            }
          }
        }
      }
      __syncthreads();

      // layer-2 partial: K-slice = this sub-chunk (128)
      for (int kt2 = 0; kt2 < 4; ++kt2){
        bf16x8 Ah[2], Al[2];
        #pragma unroll
        for (int mtl=0;mtl<2;++mtl){
          int m = (mtw+mtl)*16 + r16;
          Ah[mtl] = *(const bf16x8*)(sAF + (2080 + (kt2*4+quad)*65 + m)*8);
          Al[mtl] = *(const bf16x8*)(sAF + (2080 + 1040 + (kt2*4+quad)*65 + m)*8);
        }
        int ktAbs = kc*8 + sc*4 + kt2;       // W2 k-tile (KT=16)
        const bf16x8* Wf = (const bf16x8*)W2F;
        #pragma unroll
        for (int ntl = 0; ntl < 8; ++ntl){
          int nt = nth*8 + ntl;              // 0..15 (NT=16)
          bf16x8 Bh = Wf[(ktAbs*16 + nt)*64 + l];
          bf16x8 Bl = Wf[(16*16*64) + (ktAbs*16 + nt)*64 + l];
          f32x4 c0 = C2[ntl*2+0], c1 = C2[ntl*2+1];
          c0 = MFMA(Ah[0], Bh, c0); c1 = MFMA(Ah[1], Bh, c1);
          c0 = MFMA(Ah[0], Bl, c0); c1 = MFMA(Ah[1], Bl, c1);
          c0 = MFMA(Al[0], Bh, c0); c1 = MFMA(Al[1], Bh, c1);
          C2[ntl*2+0] = c0; C2[ntl*2+1] = c1;
        }
      }
    }
  }

  // ---- C2 epilogue: h2 = elu(C2+b2) -> A3 (all waves parallel) ----
  __syncthreads();
  #pragma unroll
  for (int ntl = 0; ntl < 8; ++ntl){
    #pragma unroll
    for (int mtl = 0; mtl < 2; ++mtl){
      f32x4 v = C2[ntl*2+mtl];
      int n2 = (nth*8 + ntl)*16 + r16;       // 0..255
      float bv = b2[n2];
      ushort hi[4], lo[4];
      #pragma unroll
      for (int r=0;r<4;++r){
        float f = elu_f(v[r] + bv);
        hi[r] = bf16_rne(f);
        float fh = __uint_as_float(((uint)hi[r])<<16);
        lo[r] = bf16_rne(f - fh);
      }
      int kg = n2 >> 3, j = n2 & 7, jj = (j & ~1) >> 1;
      int m0 = (mtw+mtl)*16 + quad*4;
      uint v01h = (uint)hi[0] | ((uint)hi[1]<<16);
      uint v23h = (uint)hi[2] | ((uint)hi[3]<<16);
      uint v01l = (uint)lo[0] | ((uint)lo[1]<<16);
      uint v23l = (uint)lo[2] | ((uint)lo[3]<<16);
      uint t01h = __shfl_xor(v01h, 1), t23h = __shfl_xor(v23h, 1);
      uint t01l = __shfl_xor(v01l, 1), t23l = __shfl_xor(v23l, 1);
      int cbH = 0*2080 + kg*65, cbL = 2080 + kg*65;   // A3 spans both halves
      if (!(l & 1)){
        ldsu[(cbH + m0 + 0)*4 + jj] = (v01h & 0xFFFFu) | (t01h << 16);
        ldsu[(cbH + m0 + 1)*4 + jj] = (v01h >> 16) | (t01h & 0xFFFF0000u);
        ldsu[(cbL + m0 + 0)*4 + jj] = (v01l & 0xFFFFu) | (t01l << 16);
        ldsu[(cbL + m0 + 1)*4 + jj] = (v01l >> 16) | (t01l & 0xFFFF0000u);
      } else {
        ldsu[(cbH + m0 + 2)*4 + jj] = (t23h & 0xFFFFu) | (v23h << 16);
        ldsu[(cbH + m0 + 3)*4 + jj] = (t23h >> 16) | (v23h & 0xFFFF0000u);
        ldsu[(cbL + m0 + 2)*4 + jj] = (t23l & 0xFFFFu) | (v23l << 16);
        ldsu[(cbL + m0 + 3)*4 + jj] = (t23l >> 16) | (v23l & 0xFFFF0000u);
      }
    }
  }
  __syncthreads();

  // ---- layer 3: C3 = A3 @ W3 (K=256, no activation) ----
  f32x4 C3[8];
  #pragma unroll
  for (int i=0;i<8;++i) C3[i] = (f32x4)0.f;
  for (int kt = 0; kt < 8; ++kt){
    bf16x8 Ah[2], Al[2];
    #pragma unroll
    for (int mtl=0;mtl<2;++mtl){
      int m = (mtw+mtl)*16 + r16;
      Ah[mtl] = *(const bf16x8*)(sAF + ((kt*4+quad)*65 + m)*8);
      Al[mtl] = *(const bf16x8*)(sAF + (2080 + (kt*4+quad)*65 + m)*8);
    }
    const bf16x8* Wf = (const bf16x8*)W3F;
    #pragma unroll
    for (int ntl = 0; ntl < 4; ++ntl){
      int nt = nth*4 + ntl;                  // 0..7 (NT=8)
      bf16x8 Bh = Wf[(kt*8 + nt)*64 + l];
      bf16x8 Bl = Wf[(8*8*64) + (kt*8 + nt)*64 + l];
      f32x4 c0 = C3[ntl*2+0], c1 = C3[ntl*2+1];
      c0 = MFMA(Ah[0], Bh, c0); c1 = MFMA(Ah[1], Bh, c1);
      c0 = MFMA(Ah[0], Bl, c0); c1 = MFMA(Ah[1], Bl, c1);
      c0 = MFMA(Al[0], Bh, c0); c1 = MFMA(Al[1], Bh, c1);
      C3[ntl*2+0] = c0; C3[ntl*2+1] = c1;
    }
  }

  // ---- C3 epilogue: h3 = C3 + b3 (NO elu) -> A4 ----
  __syncthreads();                           // all L3 reads of A3 done
  #pragma unroll
  for (int ntl = 0; ntl < 4; ++ntl){
    #pragma unroll
    for (int mtl = 0; mtl < 2; ++mtl){
      f32x4 v = C3[ntl*2+mtl];
      int n3 = (nth*4 + ntl)*16 + r16;       // 0..127
      float bv = b3[n3];
      ushort hi[4], lo[4];
      #pragma unroll
      for (int r=0;r<4;++r){
        float f = v[r] + bv;
        hi[r] = bf16_rne(f);
        float fh = __uint_as_float(((uint)hi[r])<<16);
        lo[r] = bf16_rne(f - fh);
      }
      int kg = n3 >> 3, j = n3 & 7, jj = (j & ~1) >> 1;
      int m0 = (mtw+mtl)*16 + quad*4;
      uint v01h = (uint)hi[0] | ((uint)hi[1]<<16);
      uint v23h = (uint)hi[2] | ((uint)hi[3]<<16);
      uint v01l = (uint)lo[0] | ((uint)lo[1]<<16);
      uint v23l = (uint)lo[2] | ((uint)lo[3]<<16);
      uint t01h = __shfl_xor(v01h, 1), t23h = __shfl_xor(v23h, 1);
      uint t01l = __shfl_xor(v01l, 1), t23l = __shfl_xor(v23l, 1);
      int cbH = 0*1040 + kg*65, cbL = 1040 + kg*65;    // A4 region
      if (!(l & 1)){
        ldsu[(cbH + m0 + 0)*4 + jj] = (v01h & 0xFFFFu) | (t01h << 16);
        ldsu[(cbH + m0 + 1)*4 + jj] = (v01h >> 16) | (t01h & 0xFFFF0000u);
        ldsu[(cbL + m0 + 0)*4 + jj] = (v01l & 0xFFFFu) | (t01l << 16);
        ldsu[(cbL + m0 + 1)*4 + jj] = (v01l >> 16) | (t01l & 0xFFFF0000u);
      } else {
        ldsu[(cbH + m0 + 2)*4 + jj] = (t23h & 0xFFFFu) | (v23h << 16);
        ldsu[(cbH + m0 + 3)*4 + jj] = (t23h >> 16) | (v23h & 0xFFFF0000u);
        ldsu[(cbL + m0 + 2)*4 + jj] = (t23l & 0xFFFFu) | (v23l << 16);
        ldsu[(cbL + m0 + 3)*4 + jj] = (t23l >> 16) | (v23l & 0xFFFF0000u);
      }
    }
  }
  __syncthreads();

  // ---- layer 4: C4 = A4 @ W4 (K=128) ----
  f32x4 C4[8];
  #pragma unroll
  for (int i=0;i<8;++i) C4[i] = (f32x4)0.f;
  for (int kt = 0; kt < 4; ++kt){
    bf16x8 Ah[2], Al[2];
    #pragma unroll
    for (int mtl=0;mtl<2;++mtl){
      int m = (mtw+mtl)*16 + r16;
      Ah[mtl] = *(const bf16x8*)(sAF + ((kt*4+quad)*65 + m)*8);
      Al[mtl] = *(const bf16x8*)(sAF + (1040 + (kt*4+quad)*65 + m)*8);
    }
    const bf16x8* Wf = (const bf16x8*)W4F;
    #pragma unroll
    for (int ntl = 0; ntl < 4; ++ntl){
      int nt = nth*4 + ntl;                  // 0..7 (NT=8)
      bf16x8 Bh = Wf[(kt*8 + nt)*64 + l];
      bf16x8 Bl = Wf[(4*8*64) + (kt*8 + nt)*64 + l];
      f32x4 c0 = C4[ntl*2+0], c1 = C4[ntl*2+1];
      c0 = MFMA(Ah[0], Bh, c0); c1 = MFMA(Ah[1], Bh, c1);
      c0 = MFMA(Ah[0], Bl, c0); c1 = MFMA(Ah[1], Bl, c1);
      c0 = MFMA(Al[0], Bh, c0); c1 = MFMA(Al[1], Bh, c1);
      C4[ntl*2+0] = c0; C4[ntl*2+1] = c1;
    }
  }

  // ---- layer 5: score = elu(C4+b4) . W5[:,t] ----
  float p[2][4] = {{0.f,0.f,0.f,0.f},{0.f,0.f,0.f,0.f}};
  #pragma unroll
  for (int ntl = 0; ntl < 4; ++ntl){
    int n4 = (nth*4 + ntl)*16 + r16;
    float bv = b4[n4];
    const float* w5r = W5 + n4*LL;
    #pragma unroll
    for (int mtl = 0; mtl < 2; ++mtl){
      f32x4 c = C4[ntl*2+mtl];
      #pragma unroll
      for (int r=0;r<4;++r){
        int m = (mtw+mtl)*16 + quad*4 + r;
        p[mtl][r] += elu_f(c[r] + bv) * w5r[sTy[m]];
      }
    }
  }
  #pragma unroll
  for (int d = 8; d >= 1; d >>= 1){
    #pragma unroll
    for (int mtl=0;mtl<2;++mtl)
      #pragma unroll
      for (int r=0;r<4;++r)
        p[mtl][r] += __shfl_down(p[mtl][r], d, 16);
  }
  if (r16 == 0){
    #pragma unroll
    for (int mtl=0;mtl<2;++mtl)
      #pragma unroll
      for (int r=0;r<4;++r)
        atomicAdd(&sScore[(mtw+mtl)*16 + quad*4 + r], p[mtl][r]);
  }
  __syncthreads();
  if (tid < 64){
    scores[e0 + tid] = sScore[tid] + b5[sTy[tid]];
    ebatch[e0 + tid] = sEb[tid];
  }
}

// ---------------------------------------------------------------------------
// Segment softmax / argmax passes (unchanged, verified in R1)
// ---------------------------------------------------------------------------
__global__ void kInitSeg(unsigned* segmax, float* segsum, unsigned* gmax, int* gact){
  int b = blockIdx.x*blockDim.x + threadIdx.x;
  if (b < BB){ segmax[b] = ENC_NEG_INF; segsum[b] = 0.f; gmax[b] = ENC_NEG_INF; gact[b] = 0x7FFFFFFF; }
}

__global__ __launch_bounds__(256) void kSegMax(const float* __restrict__ scores,
                                               const int* __restrict__ eb,
                                               unsigned* __restrict__ segmax){
  __shared__ unsigned l[BB];
  for (int b = threadIdx.x; b < BB; b += 256) l[b] = 0u;
  __syncthreads();
  for (int e = blockIdx.x*256 + threadIdx.x; e < EE; e += gridDim.x*256)
    atomicMax(&l[eb[e]], enc_f(scores[e]));
  __syncthreads();
  for (int b = threadIdx.x; b < BB; b += 256)
    if (l[b]) atomicMax(&segmax[b], l[b]);
}

__global__ __launch_bounds__(256) void kExpSum(const float* __restrict__ scores,
                                               const int* __restrict__ eb,
                                               const unsigned* __restrict__ segmax,
                                               float* __restrict__ segsum,
                                               float* __restrict__ outprobs){
  __shared__ float l[BB];
  for (int b = threadIdx.x; b < BB; b += 256) l[b] = 0.f;
  __syncthreads();
  for (int e = blockIdx.x*256 + threadIdx.x; e < EE; e += gridDim.x*256){
    int b = eb[e];
    float ex = expf(scores[e] - dec_f(segmax[b]));
    outprobs[e] = ex;
    atomicAdd(&l[b], ex);
  }
  __syncthreads();
  for (int b = threadIdx.x; b < BB; b += 256)
    if (l[b] != 0.f) atomicAdd(&segsum[b], l[b]);
}

__global__ __launch_bounds__(256) void kProbMax(float* __restrict__ outprobs,
                                                const int* __restrict__ eb,
                                                const float* __restrict__ segsum,
                                                unsigned* __restrict__ gmax){
  __shared__ unsigned l[BB];
  for (int b = threadIdx.x; b < BB; b += 256) l[b] = 0u;
  __syncthreads();
  for (int e = blockIdx.x*256 + threadIdx.x; e < EE; e += gridDim.x*256){
    int b = eb[e];
    float p = outprobs[e] / segsum[b];
    outprobs[e] = p;
    atomicMax(&l[b], enc_f(p));
  }
  __syncthreads();
  for (int b = threadIdx.x; b < BB; b += 256)
    if (l[b]) atomicMax(&gmax[b], l[b]);
}

__global__ __launch_bounds__(256) void kArgMin(const float* __restrict__ outprobs,
                                               const int* __restrict__ eb,
                                               const unsigned* __restrict__ gmax,
                                               int* __restrict__ gact){
  __shared__ int l[BB];
  for (int b = threadIdx.x; b < BB; b += 256) l[b] = 0x7FFFFFFF;
  __syncthreads();
  for (int e = blockIdx.x*256 + threadIdx.x; e < EE; e += gridDim.x*256){
    int b = eb[e];
    if (enc_f(outprobs[e]) == gmax[b]) atomicMin(&l[b], e);
  }
  __syncthreads();
  for (int b = threadIdx.x; b < BB; b += 256)
    if (l[b] != 0x7FFFFFFF) atomicMin(&gact[b], l[b]);
}

__global__ void kFinal(const unsigned* __restrict__ gmax, const int* __restrict__ gact,
                       float* __restrict__ out){
  int b = threadIdx.x;
  if (b < BB){
    out[EE + b]      = dec_f(gmax[b]);
    out[EE + BB + b] = (float)gact[b];
  }
}

// ---------------------------------------------------------------------------
extern "C" void kernel_launch(void* const* d_in, const int* in_sizes, int n_in,
                              void* d_out, int out_size, void* d_ws, size_t ws_size,
                              hipStream_t stream){
  const float* r0 = (const float*)d_in[0];
  const float* r1 = (const float*)d_in[1];
  const float* W1 = (const float*)d_in[2];
  const float* b1 = (const float*)d_in[3];
  const float* W2 = (const float*)d_in[4];
  const float* b2 = (const float*)d_in[5];
  const float* W3 = (const float*)d_in[6];
  const float* b3 = (const float*)d_in[7];
  const float* W4 = (const float*)d_in[8];
  const float* b4 = (const float*)d_in[9];
  const float* W5 = (const float*)d_in[10];
  const float* b5 = (const float*)d_in[11];
  const int* edge_index = (const int*)d_in[12];
  const int* batch = (const int*)d_in[13];
  const int* y = (const int*)d_in[14];
  float* out = (float*)d_out;

  char* ws = (char*)d_ws;
  size_t off = 0;
  float*    scores = (float*)(ws + off);    off += (size_t)EE*4;
  int*      ebatch = (int*)(ws + off);      off += (size_t)EE*4;
  unsigned* segmax = (unsigned*)(ws + off); off += BB*4;
  float*    segsum = (float*)(ws + off);    off += BB*4;
  unsigned* gmax   = (unsigned*)(ws + off); off += BB*4;
  int*      gact   = (int*)(ws + off);      off += BB*4;
  off = (off + 511) & ~(size_t)511;
  ushort* repsF = (ushort*)(ws + off);      off += (size_t)NN*256*2;   // 51.2 MB
  ushort* W1F   = (ushort*)(ws + off);      off += (size_t)2*8*32*512*2;
  ushort* W2F   = (ushort*)(ws + off);      off += (size_t)2*16*16*512*2;
  ushort* W3F   = (ushort*)(ws + off);      off += (size_t)2*8*8*512*2;
  ushort* W4F   = (ushort*)(ws + off);      off += (size_t)2*4*8*512*2;

  kInitSeg<<<2, 256, 0, stream>>>(segmax, segsum, gmax, gact);
  kReps<<<(NN*16)/256, 256, 0, stream>>>(r0, r1, repsF);
  kPrepW<<<(8*32*64)/256, 256, 0, stream>>>(W1, 512, 8, 32, W1F);
  kPrepW<<<(16*16*64)/256, 256, 0, stream>>>(W2, 256, 16, 16, W2F);
  kPrepW<<<(8*8*64)/256, 256, 0, stream>>>(W3, 128, 8, 8, W3F);
  kPrepW<<<(4*8*64)/256, 256, 0, stream>>>(W4, 128, 4, 8, W4F);

  kMLP<<<EE/64, 256, 0, stream>>>(repsF, W1F, W2F, W3F, W4F,
                                  b1, b2, b3, b4, W5, b5,
                                  edge_index, batch, y, scores, ebatch);

  kSegMax <<<256, 256, 0, stream>>>(scores, ebatch, segmax);
  kExpSum <<<256, 256, 0, stream>>>(scores, ebatch, segmax, segsum, out);
  kProbMax<<<256, 256, 0, stream>>>(out, ebatch, segsum, gmax);
  kArgMin <<<256, 256, 0, stream>>>(out, ebatch, gmax, gact);
  kFinal  <<<1, 512, 0, stream>>>(gmax, gact, out);
}